// Round 19
// baseline (249.546 us; speedup 1.0000x reference)
//
#include <hip/hip_runtime.h>
#include <hip/hip_bf16.h>
#include <cmath>
#include <cstdint>

typedef __hip_bfloat16 bf16;
typedef __attribute__((ext_vector_type(4))) float f32x4;
typedef __attribute__((ext_vector_type(16))) float f32x16;
typedef __attribute__((ext_vector_type(8))) short s16x8;
typedef __attribute__((ext_vector_type(4))) unsigned int u32x4;
typedef __attribute__((ext_vector_type(2))) unsigned int u32x2;

#define NB 2
#define NS 2048
#define ND 1024
#define NH 16
#define NHD 64

static __device__ __forceinline__ bf16 f2bf(float v){ return __float2bfloat16(v); }
static __device__ __forceinline__ unsigned short f2bfu(float v){
  bf16 b = __float2bfloat16(v);
  return *reinterpret_cast<unsigned short*>(&b);
}
static __device__ __forceinline__ float bfu2f(unsigned short u){
  union { unsigned int i; float f; } c; c.i = ((unsigned int)u) << 16; return c.f;
}

static __device__ __forceinline__ void gload_lds16(const void* g, void* l){
  __builtin_amdgcn_global_load_lds((const __attribute__((address_space(1))) void*)g,
                                   (__attribute__((address_space(3))) void*)l, 16, 0, 0);
}

// ---------------- prep kernels ----------------

__global__ __launch_bounds__(256) void convert_kernel(const float* __restrict__ src,
                                                       unsigned short* __restrict__ dst, int n4){
  int i = blockIdx.x * 256 + threadIdx.x;
  if (i >= n4) return;
  float4 v = ((const float4*)src)[i];
  ushort4 o;
  o.x = f2bfu(v.x); o.y = f2bfu(v.y); o.z = f2bfu(v.z); o.w = f2bfu(v.w);
  ((ushort4*)dst)[i] = o;
}

// src fp32 [R][C] -> dst bf16 [C][R]
__global__ __launch_bounds__(256) void transpose_convert(const float* __restrict__ src,
                                                          bf16* __restrict__ dst, int R, int C){
  __shared__ float tile[32][33];
  int c0 = blockIdx.x * 32, r0 = blockIdx.y * 32;
  int tx = threadIdx.x & 31, ty = threadIdx.x >> 5;
  #pragma unroll
  for (int i = ty; i < 32; i += 8)
    tile[i][tx] = src[(size_t)(r0 + i) * C + c0 + tx];
  __syncthreads();
  #pragma unroll
  for (int i = ty; i < 32; i += 8)
    dst[(size_t)(c0 + i) * R + r0 + tx] = f2bf(tile[tx][i]);
}

__global__ void pack_bias_kernel(const float* __restrict__ bq, const float* __restrict__ bk,
                                 const float* __restrict__ bv, float* __restrict__ dst){
  int i = blockIdx.x * 256 + threadIdx.x;
  if (i < 1024) dst[i] = bq[i];
  else if (i < 2048) dst[i] = bk[i - 1024];
  else if (i < 3072) dst[i] = bv[i - 2048];
}

// ------- GEMM: BMx128 tile, BK=64, swizzled staging, single barrier per K-tile -------
// (R14-verified: coalesced staging, zero bank conflicts, 2-3 blocks/CU)
// EPI: 0 = bias, 1 = QKV (q->qkv, k->kP[bh][s][64], v->vB[bh][t][d][32]),
//      2 = bias+GELU, 3 = split-K=4 bf16 partial (grid 1024: kc=s>>8, no bias)
template<int EPI, int BM>
__global__ __launch_bounds__(256, (BM == 64) ? 3 : 2)
void gemm_bf16(const bf16* __restrict__ A, const bf16* __restrict__ BT,
               const float* __restrict__ bias, bf16* __restrict__ C,
               bf16* __restrict__ kP, bf16* __restrict__ vB,
               char* __restrict__ wsbase, int M, int N, int K)
{
  constexpr int MF = BM / 32;                     // m-frags per wave
  __shared__ bf16 As[2][BM * 64];
  __shared__ bf16 Bs[2][128 * 64];

  const int tid = threadIdx.x;
  const int lane = tid & 63, wave = tid >> 6;
  const int lr = lane & 15, lg = lane >> 4;
  const int wm = wave >> 1, wn = wave & 1;

  const int nwg = gridDim.x, wg = blockIdx.x;
  const int s = (wg & 7) * (nwg >> 3) + (wg >> 3);   // nwg % 8 == 0 everywhere

  int m0, n0, kbase, NT, ldo;
  bf16* outp;
  if (EPI == 3){
    const int kc = s >> 8, tile = s & 255;        // grid 1024: 4 kc x 256 tiles
    m0 = (tile >> 3) << 7; n0 = (tile & 7) << 7;
    kbase = kc << 10; NT = 16;
    size_t off = (kc < 2) ? (size_t)kc * 8388608u
                          : 33566720u + (size_t)(kc - 2) * 8388608u;
    outp = (bf16*)(wsbase + off); ldo = 1024;
  } else {
    const int nbx = N >> 7;
    m0 = (s / nbx) * BM; n0 = (s % nbx) << 7;
    kbase = 0; NT = K >> 6;
    outp = C; ldo = N;
  }

  auto stage = [&](int t, int buf){
    const int k0 = kbase + (t << 6);
    #pragma unroll
    for (int j = 0; j < BM / 32; ++j){            // A: BM*8 16B-units
      const int bi = j * 256 + tid;
      const int row = bi >> 3, slot = bi & 7;
      const int ss = slot ^ (row & 7);
      gload_lds16(A + (size_t)(m0 + row) * K + k0 + ss * 8,
                  (char*)(&As[buf][0]) + bi * 16);
    }
    #pragma unroll
    for (int j = 0; j < 4; ++j){                  // B: 1024 16B-units
      const int bi = j * 256 + tid;
      const int row = bi >> 3, slot = bi & 7;
      const int ss = slot ^ (row & 7);
      gload_lds16(BT + (size_t)(n0 + row) * K + k0 + ss * 8,
                  (char*)(&Bs[buf][0]) + bi * 16);
    }
  };

  f32x4 acc[MF][4] = {};
  const int rsx = lr & 7;

  stage(0, 0);
  __syncthreads();

  #pragma unroll 1
  for (int G = 0; G < NT; ++G){
    const int X = G & 1;
    if (G + 1 < NT) stage(G + 1, X ^ 1);          // in flight across this tile's compute

    s16x8 bfr[4][2];
    #pragma unroll
    for (int n = 0; n < 4; ++n){
      const int rowb = wn * 64 + n * 16 + lr;
      #pragma unroll
      for (int kk = 0; kk < 2; ++kk){
        const int slot = ((kk << 2) + lg) ^ rsx;
        bfr[n][kk] = *(const s16x8*)((const char*)(&Bs[X][0]) + rowb * 128 + slot * 16);
      }
    }
    #pragma unroll
    for (int m = 0; m < MF; ++m){
      s16x8 af[2];
      const int rowa = wm * (BM / 2) + m * 16 + lr;
      #pragma unroll
      for (int kk = 0; kk < 2; ++kk){
        const int slot = ((kk << 2) + lg) ^ rsx;
        af[kk] = *(const s16x8*)((const char*)(&As[X][0]) + rowa * 128 + slot * 16);
      }
      #pragma unroll
      for (int n = 0; n < 4; ++n){
        acc[m][n] = __builtin_amdgcn_mfma_f32_16x16x32_bf16(af[0], bfr[n][0], acc[m][n], 0, 0, 0);
        acc[m][n] = __builtin_amdgcn_mfma_f32_16x16x32_bf16(af[1], bfr[n][1], acc[m][n], 0, 0, 0);
      }
    }
    __syncthreads();                               // single barrier per K-tile
  }

  // ---- epilogue ----
  if (EPI == 1 && n0 >= 2048){
    // V block: packed 8B write into tile-blocked vB[bh][sq>>5][d][sq&31]
    #pragma unroll
    for (int n = 0; n < 4; ++n){
      const int col = n0 + wn * 64 + n * 16 + lr;
      const float bv = bias[col];
      const int c2 = col - 2048, h = c2 >> 6, d = c2 & 63;
      #pragma unroll
      for (int m = 0; m < MF; ++m){
        const int row = m0 + wm * (BM / 2) + m * 16 + lg * 4;
        const int b = row >> 11, sq = row & 2047;
        unsigned int lo = (unsigned int)f2bfu(acc[m][n][0] + bv) | ((unsigned int)f2bfu(acc[m][n][1] + bv) << 16);
        unsigned int hi2 = (unsigned int)f2bfu(acc[m][n][2] + bv) | ((unsigned int)f2bfu(acc[m][n][3] + bv) << 16);
        u32x2 val; val[0] = lo; val[1] = hi2;
        const size_t idx = (((size_t)(b * NH + h) * 64 + (sq >> 5)) * 64 + d) * 32 + (sq & 31);
        *(u32x2*)&vB[idx] = val;
      }
    }
  } else if (EPI == 1 && n0 >= 1024){
    // K block: scalar writes into packed kP[bh][sq][d] (128B rows)
    #pragma unroll
    for (int n = 0; n < 4; ++n){
      const int col = n0 + wn * 64 + n * 16 + lr;
      const float bv = bias[col];
      const int c2 = col - 1024, h = c2 >> 6, d = c2 & 63;
      #pragma unroll
      for (int m = 0; m < MF; ++m){
        #pragma unroll
        for (int r = 0; r < 4; ++r){
          const int row = m0 + wm * (BM / 2) + m * 16 + lg * 4 + r;
          const int b = row >> 11, sq = row & 2047;
          kP[((size_t)(b * NH + h) * 2048 + sq) * 64 + d] = f2bf(acc[m][n][r] + bv);
        }
      }
    }
  } else {
    #pragma unroll
    for (int n = 0; n < 4; ++n){
      const int col = n0 + wn * 64 + n * 16 + lr;
      const float bv = (EPI == 3) ? 0.f : bias[col];
      #pragma unroll
      for (int m = 0; m < MF; ++m){
        #pragma unroll
        for (int r = 0; r < 4; ++r){
          const int row = m0 + wm * (BM / 2) + m * 16 + lg * 4 + r;
          float v = acc[m][n][r] + bv;
          if (EPI == 2) v = 0.5f * v * (1.f + erff(v * 0.70710678118f));
          outp[(size_t)row * ldo + col] = f2bf(v);
        }
      }
    }
  }
}

// ------- flash attention: strip-pair block, 8 waves (4 key-quarters x 2 strips) -------
// qkv: [4096][3072] bf16 (q cols only), kP: [bh][2048][64], vB: [bh][64][64][32]
// Block = pair (63-p, p): waves 0-3 = key-quarters of long strip, 4-7 = short strip.
// All blocks hold exactly 65 tiles; p ascending -> longest blocks dispatch first.
// 8192 waves -> 8 waves/SIMD nominal. VGPR ~52 (single strip/wave), (512,4) cap 64.
__global__ __launch_bounds__(512, 4)
void attn_kernel(const bf16* __restrict__ qkv, const bf16* __restrict__ kP,
                 const bf16* __restrict__ vB, bf16* __restrict__ out)
{
  const int j = blockIdx.x;
  const int bh = j & 31, p = j >> 5;           // bh -> XCD pinned; p=0 (longest) first
  const int b = bh >> 4, h = bh & 15;
  const int tid = threadIdx.x, lane = tid & 63, wave = tid >> 6;
  const int l31 = lane & 31, hi = lane >> 5;
  const int sidx = wave >> 2, q = wave & 3;    // strip-select, key-quarter
  const int strip = sidx ? p : (63 - p);
  const int q0 = strip * 32;

  __shared__ float Ob[2][32 * 64];
  __shared__ float Lb[2][32];

  auto scale8 = [](s16x8 v){
    s16x8 o;
    #pragma unroll
    for (int i = 0; i < 8; ++i){
      unsigned short u = (unsigned short)v[i];
      unsigned short e = u & 0x7F80;
      o[i] = (short)(e > (3 << 7) ? (unsigned short)(u - (3 << 7)) : (unsigned short)(u & 0x8000));
    }
    return o;
  };

  const bf16* qbase = qkv + (size_t)(b * NS + q0 + l31) * 3072 + h * 64 + hi * 8;
  s16x8 qf[4];
  #pragma unroll
  for (int kk = 0; kk < 4; ++kk)
    qf[kk] = scale8(*(const s16x8*)(qbase + kk * 16));

  const bf16* kpb = kP + (size_t)bh * 2048 * 64;
  const bf16* vbb = vB + (size_t)bh * 64 * 64 * 32;

  f32x16 oacc0 = {}, oacc1 = {};
  float lsum = 0.f;

  #pragma unroll 1
  for (int t = q; t <= strip; t += 4){
    const bf16* krow = kpb + (size_t)(t * 32 + l31) * 64 + hi * 8;
    s16x8 kf0 = *(const s16x8*)(krow);
    s16x8 kf1 = *(const s16x8*)(krow + 16);
    s16x8 kf2 = *(const s16x8*)(krow + 32);
    s16x8 kf3 = *(const s16x8*)(krow + 48);
    const bf16* vt0 = vbb + ((size_t)t * 64 + l31) * 32 + hi * 8;
    const bf16* vt1 = vbb + ((size_t)t * 64 + 32 + l31) * 32 + hi * 8;
    s16x8 vf00 = *(const s16x8*)(vt0);
    s16x8 vf10 = *(const s16x8*)(vt0 + 16);
    s16x8 vf01 = *(const s16x8*)(vt1);
    s16x8 vf11 = *(const s16x8*)(vt1 + 16);

    f32x16 sacc = {};
    sacc = __builtin_amdgcn_mfma_f32_32x32x16_bf16(kf0, qf[0], sacc, 0, 0, 0);
    sacc = __builtin_amdgcn_mfma_f32_32x32x16_bf16(kf1, qf[1], sacc, 0, 0, 0);
    sacc = __builtin_amdgcn_mfma_f32_32x32x16_bf16(kf2, qf[2], sacc, 0, 0, 0);
    sacc = __builtin_amdgcn_mfma_f32_32x32x16_bf16(kf3, qf[3], sacc, 0, 0, 0);

    const bool dg = (t == strip);
    float pv[16];
    #pragma unroll
    for (int r = 0; r < 16; ++r){
      const int kloc = (r & 3) + 8 * (r >> 2) + 4 * hi;
      float e = __expf(sacc[r]);
      if (dg && kloc > l31) e = 0.f;
      pv[r] = e;
      lsum += e;
    }
    unsigned int w[8];
    #pragma unroll
    for (int i = 0; i < 8; ++i)
      w[i] = (unsigned int)f2bfu(pv[2 * i]) | ((unsigned int)f2bfu(pv[2 * i + 1]) << 16);
    unsigned int s0 = hi ? w[0] : w[2];
    unsigned int s1 = hi ? w[1] : w[3];
    unsigned int s2 = hi ? w[4] : w[6];
    unsigned int s3 = hi ? w[5] : w[7];
    unsigned int g0 = (unsigned int)__shfl_xor((int)s0, 32);
    unsigned int g1 = (unsigned int)__shfl_xor((int)s1, 32);
    unsigned int g2 = (unsigned int)__shfl_xor((int)s2, 32);
    unsigned int g3 = (unsigned int)__shfl_xor((int)s3, 32);
    union { u32x4 u; s16x8 s; } pa0, pa1;
    if (hi == 0){
      pa0.u[0] = w[0]; pa0.u[1] = w[1]; pa0.u[2] = g0; pa0.u[3] = g1;
      pa1.u[0] = w[4]; pa1.u[1] = w[5]; pa1.u[2] = g2; pa1.u[3] = g3;
    } else {
      pa0.u[0] = g0; pa0.u[1] = g1; pa0.u[2] = w[2]; pa0.u[3] = w[3];
      pa1.u[0] = g2; pa1.u[1] = g3; pa1.u[2] = w[6]; pa1.u[3] = w[7];
    }
    oacc0 = __builtin_amdgcn_mfma_f32_32x32x16_bf16(pa0.s, vf00, oacc0, 0, 0, 0);
    oacc0 = __builtin_amdgcn_mfma_f32_32x32x16_bf16(pa1.s, vf10, oacc0, 0, 0, 0);
    oacc1 = __builtin_amdgcn_mfma_f32_32x32x16_bf16(pa0.s, vf01, oacc1, 0, 0, 0);
    oacc1 = __builtin_amdgcn_mfma_f32_32x32x16_bf16(pa1.s, vf11, oacc1, 0, 0, 0);
  }

  lsum += __shfl_xor(lsum, 32);                // per-q over this wave's tiles

  // serialized cross-wave accumulate: round r handles quarter r of BOTH strips
  #pragma unroll 1
  for (int r = 0; r < 4; ++r){
    if (q == r){
      if (r == 0){
        #pragma unroll
        for (int k = 0; k < 16; ++k){
          const int rowq = (k & 3) + 8 * (k >> 2) + 4 * hi;
          Ob[sidx][rowq * 64 + l31] = oacc0[k];
          Ob[sidx][rowq * 64 + 32 + l31] = oacc1[k];
        }
        if (hi == 0) Lb[sidx][l31] = lsum;
      } else {
        #pragma unroll
        for (int k = 0; k < 16; ++k){
          const int rowq = (k & 3) + 8 * (k >> 2) + 4 * hi;
          Ob[sidx][rowq * 64 + l31] += oacc0[k];
          Ob[sidx][rowq * 64 + 32 + l31] += oacc1[k];
        }
        if (hi == 0) Lb[sidx][l31] += lsum;
      }
    }
    __syncthreads();
  }

  // cooperative coalesced store of both strips
  #pragma unroll
  for (int i = 0; i < 8; ++i){
    const int e = i * 512 + tid;                 // 0..4095
    const int si = e >> 11, rem = e & 2047;
    const int row = rem >> 6, col = rem & 63;
    const int st = si ? p : (63 - p);
    out[(size_t)(b * NS + st * 32 + row) * ND + h * 64 + col] = f2bf(Ob[si][rem] / Lb[si][row]);
  }
}

// ---------------- residual + 4-partial combine + b2 + LayerNorm ----------------
__global__ __launch_bounds__(256)
void ln_kernel(const bf16* __restrict__ a, const bf16* __restrict__ p0,
               const bf16* __restrict__ p1, const bf16* __restrict__ p2,
               const bf16* __restrict__ p3, const float* __restrict__ badd,
               const float* __restrict__ gamma, const float* __restrict__ beta,
               float* __restrict__ out)
{
  const int row = blockIdx.x;
  const int tid = threadIdx.x;
  const int lane = tid & 63, wave = tid >> 6;
  const size_t base = (size_t)row * ND;
  ushort4 ua = *(const ushort4*)((const unsigned short*)a  + base + tid * 4);
  ushort4 u0 = *(const ushort4*)((const unsigned short*)p0 + base + tid * 4);
  ushort4 u1 = *(const ushort4*)((const unsigned short*)p1 + base + tid * 4);
  ushort4 u2 = *(const ushort4*)((const unsigned short*)p2 + base + tid * 4);
  ushort4 u3 = *(const ushort4*)((const unsigned short*)p3 + base + tid * 4);
  float4 vb = *(const float4*)(badd + tid * 4);
  float y[4];
  y[0] = bfu2f(ua.x) + bfu2f(u0.x) + bfu2f(u1.x) + bfu2f(u2.x) + bfu2f(u3.x) + vb.x;
  y[1] = bfu2f(ua.y) + bfu2f(u0.y) + bfu2f(u1.y) + bfu2f(u2.y) + bfu2f(u3.y) + vb.y;
  y[2] = bfu2f(ua.z) + bfu2f(u0.z) + bfu2f(u1.z) + bfu2f(u2.z) + bfu2f(u3.z) + vb.z;
  y[3] = bfu2f(ua.w) + bfu2f(u0.w) + bfu2f(u1.w) + bfu2f(u2.w) + bfu2f(u3.w) + vb.w;
  float s = y[0] + y[1] + y[2] + y[3];
  float ss = y[0]*y[0] + y[1]*y[1] + y[2]*y[2] + y[3]*y[3];
  #pragma unroll
  for (int off = 1; off < 64; off <<= 1){
    s  += __shfl_xor(s, off);
    ss += __shfl_xor(ss, off);
  }
  __shared__ float rs[4], rss[4];
  if (lane == 0){ rs[wave] = s; rss[wave] = ss; }
  __syncthreads();
  const float S  = rs[0] + rs[1] + rs[2] + rs[3];
  const float SS = rss[0] + rss[1] + rss[2] + rss[3];
  const float mu = S * (1.f / 1024.f);
  const float var = SS * (1.f / 1024.f) - mu * mu;
  const float inv = rsqrtf(var + 1e-6f);
  #pragma unroll
  for (int jj = 0; jj < 4; ++jj){
    int c = tid * 4 + jj;
    out[base + c] = (y[jj] - mu) * inv * gamma[c] + beta[c];
  }
}

// ---------------- launcher ----------------
extern "C" void kernel_launch(void* const* d_in, const int* in_sizes, int n_in,
                              void* d_out, int out_size, void* d_ws, size_t ws_size,
                              hipStream_t stream)
{
  (void)in_sizes; (void)n_in; (void)out_size; (void)ws_size;
  const float* x  = (const float*)d_in[0];
  const float* Wq = (const float*)d_in[2];
  const float* bq = (const float*)d_in[3];
  const float* Wk = (const float*)d_in[4];
  const float* bk = (const float*)d_in[5];
  const float* Wv = (const float*)d_in[6];
  const float* bv = (const float*)d_in[7];
  const float* Wo = (const float*)d_in[8];
  const float* bo = (const float*)d_in[9];
  const float* W1 = (const float*)d_in[10];
  const float* b1 = (const float*)d_in[11];
  const float* W2 = (const float*)d_in[12];
  const float* b2 = (const float*)d_in[13];
  const float* gamma = (const float*)d_in[14];
  const float* beta  = (const float*)d_in[15];
  float* out = (float*)d_out;

  char* ws = (char*)d_ws;
  bf16* x_bf    = (bf16*)(ws + 0);          //  8,388,608  (freed after QKV)
  bf16* wqkvT   = (bf16*)(ws + 8388608);    //  6,291,456  (freed after QKV)
  bf16* woT     = (bf16*)(ws + 14680064);   //  2,097,152
  bf16* w1T     = (bf16*)(ws + 16777216);   //  8,388,608
  bf16* w2T     = (bf16*)(ws + 25165824);   //  8,388,608
  float* bqkv   = (float*)(ws + 33554432);  //     12,288
  bf16* qkv     = (bf16*)(ws + 33566720);   // 25,165,824  (q cols only; freed after attn)
  bf16* vB      = (bf16*)(ws + 58732544);   //  8,388,608  (freed after attn)
  bf16* attn    = (bf16*)(ws + 67121152);   //  8,388,608
  bf16* attnout = (bf16*)(ws + 75509760);   //  8,388,608
  bf16* hbuf    = (bf16*)(ws + 92286976);   // 33,554,432
  bf16* kP      = (bf16*)(ws + 92286976);   //  8,388,608 (hbuf head; attn done before W1 writes)
  // W2 split-K=4 bf16 partials in freed regions:
  bf16* P0 = (bf16*)(ws + 0);               // x_bf
  bf16* P1 = (bf16*)(ws + 8388608);         // wqkvT
  bf16* P2 = (bf16*)(ws + 33566720);        // qkv (first 8 MB)
  bf16* P3 = (bf16*)(ws + 41955328);        // qkv (next 8 MB)

  convert_kernel<<<4096, 256, 0, stream>>>(x, (unsigned short*)x_bf, 1048576);
  transpose_convert<<<dim3(32, 32), 256, 0, stream>>>(Wq, wqkvT,               1024, 1024);
  transpose_convert<<<dim3(32, 32), 256, 0, stream>>>(Wk, wqkvT + 1024 * 1024, 1024, 1024);
  transpose_convert<<<dim3(32, 32), 256, 0, stream>>>(Wv, wqkvT + 2048 * 1024, 1024, 1024);
  transpose_convert<<<dim3(32, 32), 256, 0, stream>>>(Wo, woT, 1024, 1024);
  transpose_convert<<<dim3(128, 32), 256, 0, stream>>>(W1, w1T, 1024, 4096);
  transpose_convert<<<dim3(32, 128), 256, 0, stream>>>(W2, w2T, 4096, 1024);
  pack_bias_kernel<<<12, 256, 0, stream>>>(bq, bk, bv, bqkv);

  gemm_bf16<1, 128><<<768, 256, 0, stream>>>(x_bf, wqkvT, bqkv, qkv, kP, vB, nullptr, 4096, 3072, 1024);
  attn_kernel<<<dim3(1024), 512, 0, stream>>>(qkv, kP, vB, attn);
  gemm_bf16<0, 64><<<512, 256, 0, stream>>>(attn, woT, bo, attnout, nullptr, nullptr, nullptr, 4096, 1024, 1024);
  gemm_bf16<2, 128><<<1024, 256, 0, stream>>>(attnout, w1T, b1, hbuf, nullptr, nullptr, nullptr, 4096, 4096, 1024);
  gemm_bf16<3, 128><<<1024, 256, 0, stream>>>(hbuf, w2T, nullptr, nullptr, nullptr, nullptr, ws, 4096, 1024, 4096);
  ln_kernel<<<4096, 256, 0, stream>>>(attnout, P0, P1, P2, P3, b2, gamma, beta, out);
}

// Round 20
// 237.064 us; speedup vs baseline: 1.0526x; 1.0526x over previous
//
#include <hip/hip_runtime.h>
#include <hip/hip_bf16.h>
#include <cmath>
#include <cstdint>

typedef __hip_bfloat16 bf16;
typedef __attribute__((ext_vector_type(4))) float f32x4;
typedef __attribute__((ext_vector_type(16))) float f32x16;
typedef __attribute__((ext_vector_type(8))) short s16x8;
typedef __attribute__((ext_vector_type(4))) unsigned int u32x4;
typedef __attribute__((ext_vector_type(2))) unsigned int u32x2;

#define NB 2
#define NS 2048
#define ND 1024
#define NH 16
#define NHD 64

static __device__ __forceinline__ bf16 f2bf(float v){ return __float2bfloat16(v); }
static __device__ __forceinline__ unsigned short f2bfu(float v){
  bf16 b = __float2bfloat16(v);
  return *reinterpret_cast<unsigned short*>(&b);
}
static __device__ __forceinline__ float bfu2f(unsigned short u){
  union { unsigned int i; float f; } c; c.i = ((unsigned int)u) << 16; return c.f;
}

static __device__ __forceinline__ void gload_lds16(const void* g, void* l){
  __builtin_amdgcn_global_load_lds((const __attribute__((address_space(1))) void*)g,
                                   (__attribute__((address_space(3))) void*)l, 16, 0, 0);
}

// ---------------- prep kernels ----------------

__global__ __launch_bounds__(256) void convert_kernel(const float* __restrict__ src,
                                                       unsigned short* __restrict__ dst, int n4){
  int i = blockIdx.x * 256 + threadIdx.x;
  if (i >= n4) return;
  float4 v = ((const float4*)src)[i];
  ushort4 o;
  o.x = f2bfu(v.x); o.y = f2bfu(v.y); o.z = f2bfu(v.z); o.w = f2bfu(v.w);
  ((ushort4*)dst)[i] = o;
}

// src fp32 [R][C] -> dst bf16 [C][R]
__global__ __launch_bounds__(256) void transpose_convert(const float* __restrict__ src,
                                                          bf16* __restrict__ dst, int R, int C){
  __shared__ float tile[32][33];
  int c0 = blockIdx.x * 32, r0 = blockIdx.y * 32;
  int tx = threadIdx.x & 31, ty = threadIdx.x >> 5;
  #pragma unroll
  for (int i = ty; i < 32; i += 8)
    tile[i][tx] = src[(size_t)(r0 + i) * C + c0 + tx];
  __syncthreads();
  #pragma unroll
  for (int i = ty; i < 32; i += 8)
    dst[(size_t)(c0 + i) * R + r0 + tx] = f2bf(tile[tx][i]);
}

// batched 1024x1024 transpose-convert: z selects {Wq,Wk,Wv,Wo}
__global__ __launch_bounds__(256) void transpose4_convert(
    const float* __restrict__ s0, const float* __restrict__ s1,
    const float* __restrict__ s2, const float* __restrict__ s3,
    bf16* __restrict__ d0, bf16* __restrict__ d1,
    bf16* __restrict__ d2, bf16* __restrict__ d3){
  __shared__ float tile[32][33];
  const int z = blockIdx.z;
  const float* src = (z == 0) ? s0 : (z == 1) ? s1 : (z == 2) ? s2 : s3;
  bf16* dst = (z == 0) ? d0 : (z == 1) ? d1 : (z == 2) ? d2 : d3;
  int c0 = blockIdx.x * 32, r0 = blockIdx.y * 32;
  int tx = threadIdx.x & 31, ty = threadIdx.x >> 5;
  #pragma unroll
  for (int i = ty; i < 32; i += 8)
    tile[i][tx] = src[(size_t)(r0 + i) * 1024 + c0 + tx];
  __syncthreads();
  #pragma unroll
  for (int i = ty; i < 32; i += 8)
    dst[(size_t)(c0 + i) * 1024 + r0 + tx] = f2bf(tile[tx][i]);
}

__global__ void pack_bias_kernel(const float* __restrict__ bq, const float* __restrict__ bk,
                                 const float* __restrict__ bv, float* __restrict__ dst){
  int i = blockIdx.x * 256 + threadIdx.x;
  if (i < 1024) dst[i] = bq[i];
  else if (i < 2048) dst[i] = bk[i - 1024];
  else if (i < 3072) dst[i] = bv[i - 2048];
}

// ------- GEMM: BMx128 tile, BK=64, swizzled staging, single barrier per K-tile -------
// (R14-verified: coalesced staging, zero bank conflicts, 2-3 blocks/CU)
// EPI: 0 = bias, 1 = QKV (q->qkv, k->kP[bh][s][64], v->vB[bh][t][d][32]),
//      2 = bias+GELU, 3 = split-K=4 bf16 partial (grid 1024: kc=s>>8, no bias)
template<int EPI, int BM>
__global__ __launch_bounds__(256, (BM == 64) ? 3 : 2)
void gemm_bf16(const bf16* __restrict__ A, const bf16* __restrict__ BT,
               const float* __restrict__ bias, bf16* __restrict__ C,
               bf16* __restrict__ kP, bf16* __restrict__ vB,
               char* __restrict__ wsbase, int M, int N, int K)
{
  constexpr int MF = BM / 32;                     // m-frags per wave
  __shared__ bf16 As[2][BM * 64];
  __shared__ bf16 Bs[2][128 * 64];

  const int tid = threadIdx.x;
  const int lane = tid & 63, wave = tid >> 6;
  const int lr = lane & 15, lg = lane >> 4;
  const int wm = wave >> 1, wn = wave & 1;

  const int nwg = gridDim.x, wg = blockIdx.x;
  const int s = (wg & 7) * (nwg >> 3) + (wg >> 3);   // nwg % 8 == 0 everywhere

  int m0, n0, kbase, NT, ldo;
  bf16* outp;
  if (EPI == 3){
    const int kc = s >> 8, tile = s & 255;        // grid 1024: 4 kc x 256 tiles
    m0 = (tile >> 3) << 7; n0 = (tile & 7) << 7;
    kbase = kc << 10; NT = 16;
    size_t off = (kc < 2) ? (size_t)kc * 8388608u
                          : 33566720u + (size_t)(kc - 2) * 8388608u;
    outp = (bf16*)(wsbase + off); ldo = 1024;
  } else {
    const int nbx = N >> 7;
    m0 = (s / nbx) * BM; n0 = (s % nbx) << 7;
    kbase = 0; NT = K >> 6;
    outp = C; ldo = N;
  }

  auto stage = [&](int t, int buf){
    const int k0 = kbase + (t << 6);
    #pragma unroll
    for (int j = 0; j < BM / 32; ++j){            // A: BM*8 16B-units
      const int bi = j * 256 + tid;
      const int row = bi >> 3, slot = bi & 7;
      const int ss = slot ^ (row & 7);
      gload_lds16(A + (size_t)(m0 + row) * K + k0 + ss * 8,
                  (char*)(&As[buf][0]) + bi * 16);
    }
    #pragma unroll
    for (int j = 0; j < 4; ++j){                  // B: 1024 16B-units
      const int bi = j * 256 + tid;
      const int row = bi >> 3, slot = bi & 7;
      const int ss = slot ^ (row & 7);
      gload_lds16(BT + (size_t)(n0 + row) * K + k0 + ss * 8,
                  (char*)(&Bs[buf][0]) + bi * 16);
    }
  };

  f32x4 acc[MF][4] = {};
  const int rsx = lr & 7;

  stage(0, 0);
  __syncthreads();

  #pragma unroll 1
  for (int G = 0; G < NT; ++G){
    const int X = G & 1;
    if (G + 1 < NT) stage(G + 1, X ^ 1);          // in flight across this tile's compute

    s16x8 bfr[4][2];
    #pragma unroll
    for (int n = 0; n < 4; ++n){
      const int rowb = wn * 64 + n * 16 + lr;
      #pragma unroll
      for (int kk = 0; kk < 2; ++kk){
        const int slot = ((kk << 2) + lg) ^ rsx;
        bfr[n][kk] = *(const s16x8*)((const char*)(&Bs[X][0]) + rowb * 128 + slot * 16);
      }
    }
    #pragma unroll
    for (int m = 0; m < MF; ++m){
      s16x8 af[2];
      const int rowa = wm * (BM / 2) + m * 16 + lr;
      #pragma unroll
      for (int kk = 0; kk < 2; ++kk){
        const int slot = ((kk << 2) + lg) ^ rsx;
        af[kk] = *(const s16x8*)((const char*)(&As[X][0]) + rowa * 128 + slot * 16);
      }
      #pragma unroll
      for (int n = 0; n < 4; ++n){
        acc[m][n] = __builtin_amdgcn_mfma_f32_16x16x32_bf16(af[0], bfr[n][0], acc[m][n], 0, 0, 0);
        acc[m][n] = __builtin_amdgcn_mfma_f32_16x16x32_bf16(af[1], bfr[n][1], acc[m][n], 0, 0, 0);
      }
    }
    __syncthreads();                               // single barrier per K-tile
  }

  // ---- epilogue ----
  if (EPI == 1 && n0 >= 2048){
    // V block: packed 8B write into tile-blocked vB[bh][sq>>5][d][sq&31]
    #pragma unroll
    for (int n = 0; n < 4; ++n){
      const int col = n0 + wn * 64 + n * 16 + lr;
      const float bv = bias[col];
      const int c2 = col - 2048, h = c2 >> 6, d = c2 & 63;
      #pragma unroll
      for (int m = 0; m < MF; ++m){
        const int row = m0 + wm * (BM / 2) + m * 16 + lg * 4;
        const int b = row >> 11, sq = row & 2047;
        unsigned int lo = (unsigned int)f2bfu(acc[m][n][0] + bv) | ((unsigned int)f2bfu(acc[m][n][1] + bv) << 16);
        unsigned int hi2 = (unsigned int)f2bfu(acc[m][n][2] + bv) | ((unsigned int)f2bfu(acc[m][n][3] + bv) << 16);
        u32x2 val; val[0] = lo; val[1] = hi2;
        const size_t idx = (((size_t)(b * NH + h) * 64 + (sq >> 5)) * 64 + d) * 32 + (sq & 31);
        *(u32x2*)&vB[idx] = val;
      }
    }
  } else if (EPI == 1 && n0 >= 1024){
    // K block: scalar writes into packed kP[bh][sq][d] (128B rows)
    #pragma unroll
    for (int n = 0; n < 4; ++n){
      const int col = n0 + wn * 64 + n * 16 + lr;
      const float bv = bias[col];
      const int c2 = col - 1024, h = c2 >> 6, d = c2 & 63;
      #pragma unroll
      for (int m = 0; m < MF; ++m){
        #pragma unroll
        for (int r = 0; r < 4; ++r){
          const int row = m0 + wm * (BM / 2) + m * 16 + lg * 4 + r;
          const int b = row >> 11, sq = row & 2047;
          kP[((size_t)(b * NH + h) * 2048 + sq) * 64 + d] = f2bf(acc[m][n][r] + bv);
        }
      }
    }
  } else {
    #pragma unroll
    for (int n = 0; n < 4; ++n){
      const int col = n0 + wn * 64 + n * 16 + lr;
      const float bv = (EPI == 3) ? 0.f : bias[col];
      #pragma unroll
      for (int m = 0; m < MF; ++m){
        #pragma unroll
        for (int r = 0; r < 4; ++r){
          const int row = m0 + wm * (BM / 2) + m * 16 + lg * 4 + r;
          float v = acc[m][n][r] + bv;
          if (EPI == 2) v = 0.5f * v * (1.f + erff(v * 0.70710678118f));
          outp[(size_t)row * ldo + col] = f2bf(v);
        }
      }
    }
  }
}

// ---------------- flash attention (R14-proven: strip-pair blocks, packed K/V) ----------------
// qkv: [4096][3072] bf16 (q cols only), kP: [bh][2048][64], vB: [bh][64][64][32]
// Block = strip-pair (63-p, p) x key-half; 4 waves, ~65 tiles total (uniform), one barrier.
__global__ __launch_bounds__(256, 3)
void attn_kernel(const bf16* __restrict__ qkv, const bf16* __restrict__ kP,
                 const bf16* __restrict__ vB, bf16* __restrict__ out)
{
  const int j = blockIdx.x;
  const int bh = j & 31, p = j >> 5;           // bh -> XCD pinned
  const int b = bh >> 4, h = bh & 15;
  const int tid = threadIdx.x, lane = tid & 63, wave = tid >> 6;
  const int l31 = lane & 31, hi = lane >> 5;
  const int strip = (wave < 2) ? (63 - p) : p;
  const int hsel = wave & 1, sidx = wave >> 1;
  const int q0 = strip * 32;

  __shared__ float Ob[2][32 * 64];
  __shared__ float Lb[2][32];

  auto scale8 = [](s16x8 v){
    s16x8 o;
    #pragma unroll
    for (int i = 0; i < 8; ++i){
      unsigned short u = (unsigned short)v[i];
      unsigned short e = u & 0x7F80;
      o[i] = (short)(e > (3 << 7) ? (unsigned short)(u - (3 << 7)) : (unsigned short)(u & 0x8000));
    }
    return o;
  };

  const bf16* qbase = qkv + (size_t)(b * NS + q0 + l31) * 3072 + h * 64 + hi * 8;
  s16x8 qf[4];
  #pragma unroll
  for (int kk = 0; kk < 4; ++kk)
    qf[kk] = scale8(*(const s16x8*)(qbase + kk * 16));

  const bf16* kpb = kP + (size_t)bh * 2048 * 64;
  const bf16* vbb = vB + (size_t)bh * 64 * 64 * 32;

  f32x16 oacc0 = {}, oacc1 = {};
  float lsum = 0.f;

  #pragma unroll 1
  for (int t = hsel; t <= strip; t += 2){
    const bf16* krow = kpb + (size_t)(t * 32 + l31) * 64 + hi * 8;
    s16x8 kf0 = *(const s16x8*)(krow);
    s16x8 kf1 = *(const s16x8*)(krow + 16);
    s16x8 kf2 = *(const s16x8*)(krow + 32);
    s16x8 kf3 = *(const s16x8*)(krow + 48);
    const bf16* vt0 = vbb + ((size_t)t * 64 + l31) * 32 + hi * 8;
    const bf16* vt1 = vbb + ((size_t)t * 64 + 32 + l31) * 32 + hi * 8;
    s16x8 vf00 = *(const s16x8*)(vt0);
    s16x8 vf10 = *(const s16x8*)(vt0 + 16);
    s16x8 vf01 = *(const s16x8*)(vt1);
    s16x8 vf11 = *(const s16x8*)(vt1 + 16);

    f32x16 sacc = {};
    sacc = __builtin_amdgcn_mfma_f32_32x32x16_bf16(kf0, qf[0], sacc, 0, 0, 0);
    sacc = __builtin_amdgcn_mfma_f32_32x32x16_bf16(kf1, qf[1], sacc, 0, 0, 0);
    sacc = __builtin_amdgcn_mfma_f32_32x32x16_bf16(kf2, qf[2], sacc, 0, 0, 0);
    sacc = __builtin_amdgcn_mfma_f32_32x32x16_bf16(kf3, qf[3], sacc, 0, 0, 0);

    const bool dg = (t == strip);
    float pv[16];
    #pragma unroll
    for (int r = 0; r < 16; ++r){
      const int kloc = (r & 3) + 8 * (r >> 2) + 4 * hi;
      float e = __expf(sacc[r]);
      if (dg && kloc > l31) e = 0.f;
      pv[r] = e;
      lsum += e;
    }
    unsigned int w[8];
    #pragma unroll
    for (int i = 0; i < 8; ++i)
      w[i] = (unsigned int)f2bfu(pv[2 * i]) | ((unsigned int)f2bfu(pv[2 * i + 1]) << 16);
    unsigned int s0 = hi ? w[0] : w[2];
    unsigned int s1 = hi ? w[1] : w[3];
    unsigned int s2 = hi ? w[4] : w[6];
    unsigned int s3 = hi ? w[5] : w[7];
    unsigned int g0 = (unsigned int)__shfl_xor((int)s0, 32);
    unsigned int g1 = (unsigned int)__shfl_xor((int)s1, 32);
    unsigned int g2 = (unsigned int)__shfl_xor((int)s2, 32);
    unsigned int g3 = (unsigned int)__shfl_xor((int)s3, 32);
    union { u32x4 u; s16x8 s; } pa0, pa1;
    if (hi == 0){
      pa0.u[0] = w[0]; pa0.u[1] = w[1]; pa0.u[2] = g0; pa0.u[3] = g1;
      pa1.u[0] = w[4]; pa1.u[1] = w[5]; pa1.u[2] = g2; pa1.u[3] = g3;
    } else {
      pa0.u[0] = g0; pa0.u[1] = g1; pa0.u[2] = w[2]; pa0.u[3] = w[3];
      pa1.u[0] = g2; pa1.u[1] = g3; pa1.u[2] = w[6]; pa1.u[3] = w[7];
    }
    oacc0 = __builtin_amdgcn_mfma_f32_32x32x16_bf16(pa0.s, vf00, oacc0, 0, 0, 0);
    oacc0 = __builtin_amdgcn_mfma_f32_32x32x16_bf16(pa1.s, vf10, oacc0, 0, 0, 0);
    oacc1 = __builtin_amdgcn_mfma_f32_32x32x16_bf16(pa0.s, vf01, oacc1, 0, 0, 0);
    oacc1 = __builtin_amdgcn_mfma_f32_32x32x16_bf16(pa1.s, vf11, oacc1, 0, 0, 0);
  }

  lsum += __shfl_xor(lsum, 32);
  if (hsel == 0){
    #pragma unroll
    for (int r = 0; r < 16; ++r){
      const int rowq = (r & 3) + 8 * (r >> 2) + 4 * hi;
      Ob[sidx][rowq * 64 + l31] = oacc0[r];
      Ob[sidx][rowq * 64 + 32 + l31] = oacc1[r];
    }
    if (hi == 0) Lb[sidx][l31] = lsum;
    __syncthreads();
  } else {
    __syncthreads();
    float lf = lsum + Lb[sidx][l31];
    if (hi == 0) Lb[sidx][l31] = lf;
    #pragma unroll
    for (int r = 0; r < 16; ++r){
      const int rowq = (r & 3) + 8 * (r >> 2) + 4 * hi;
      const float denom = Lb[sidx][rowq];
      const float o0 = oacc0[r] + Ob[sidx][rowq * 64 + l31];
      const float o1 = oacc1[r] + Ob[sidx][rowq * 64 + 32 + l31];
      const size_t rbase = (size_t)(b * NS + q0 + rowq) * ND + h * 64;
      out[rbase + l31] = f2bf(o0 / denom);
      out[rbase + 32 + l31] = f2bf(o1 / denom);
    }
  }
}

// ---------------- residual + 4-partial combine + b2 + LayerNorm ----------------
__global__ __launch_bounds__(256)
void ln_kernel(const bf16* __restrict__ a, const bf16* __restrict__ p0,
               const bf16* __restrict__ p1, const bf16* __restrict__ p2,
               const bf16* __restrict__ p3, const float* __restrict__ badd,
               const float* __restrict__ gamma, const float* __restrict__ beta,
               float* __restrict__ out)
{
  const int row = blockIdx.x;
  const int tid = threadIdx.x;
  const int lane = tid & 63, wave = tid >> 6;
  const size_t base = (size_t)row * ND;
  ushort4 ua = *(const ushort4*)((const unsigned short*)a  + base + tid * 4);
  ushort4 u0 = *(const ushort4*)((const unsigned short*)p0 + base + tid * 4);
  ushort4 u1 = *(const ushort4*)((const unsigned short*)p1 + base + tid * 4);
  ushort4 u2 = *(const ushort4*)((const unsigned short*)p2 + base + tid * 4);
  ushort4 u3 = *(const ushort4*)((const unsigned short*)p3 + base + tid * 4);
  float4 vb = *(const float4*)(badd + tid * 4);
  float y[4];
  y[0] = bfu2f(ua.x) + bfu2f(u0.x) + bfu2f(u1.x) + bfu2f(u2.x) + bfu2f(u3.x) + vb.x;
  y[1] = bfu2f(ua.y) + bfu2f(u0.y) + bfu2f(u1.y) + bfu2f(u2.y) + bfu2f(u3.y) + vb.y;
  y[2] = bfu2f(ua.z) + bfu2f(u0.z) + bfu2f(u1.z) + bfu2f(u2.z) + bfu2f(u3.z) + vb.z;
  y[3] = bfu2f(ua.w) + bfu2f(u0.w) + bfu2f(u1.w) + bfu2f(u2.w) + bfu2f(u3.w) + vb.w;
  float s = y[0] + y[1] + y[2] + y[3];
  float ss = y[0]*y[0] + y[1]*y[1] + y[2]*y[2] + y[3]*y[3];
  #pragma unroll
  for (int off = 1; off < 64; off <<= 1){
    s  += __shfl_xor(s, off);
    ss += __shfl_xor(ss, off);
  }
  __shared__ float rs[4], rss[4];
  if (lane == 0){ rs[wave] = s; rss[wave] = ss; }
  __syncthreads();
  const float S  = rs[0] + rs[1] + rs[2] + rs[3];
  const float SS = rss[0] + rss[1] + rss[2] + rss[3];
  const float mu = S * (1.f / 1024.f);
  const float var = SS * (1.f / 1024.f) - mu * mu;
  const float inv = rsqrtf(var + 1e-6f);
  #pragma unroll
  for (int jj = 0; jj < 4; ++jj){
    int c = tid * 4 + jj;
    out[base + c] = (y[jj] - mu) * inv * gamma[c] + beta[c];
  }
}

// ---------------- launcher ----------------
extern "C" void kernel_launch(void* const* d_in, const int* in_sizes, int n_in,
                              void* d_out, int out_size, void* d_ws, size_t ws_size,
                              hipStream_t stream)
{
  (void)in_sizes; (void)n_in; (void)out_size; (void)ws_size;
  const float* x  = (const float*)d_in[0];
  const float* Wq = (const float*)d_in[2];
  const float* bq = (const float*)d_in[3];
  const float* Wk = (const float*)d_in[4];
  const float* bk = (const float*)d_in[5];
  const float* Wv = (const float*)d_in[6];
  const float* bv = (const float*)d_in[7];
  const float* Wo = (const float*)d_in[8];
  const float* bo = (const float*)d_in[9];
  const float* W1 = (const float*)d_in[10];
  const float* b1 = (const float*)d_in[11];
  const float* W2 = (const float*)d_in[12];
  const float* b2 = (const float*)d_in[13];
  const float* gamma = (const float*)d_in[14];
  const float* beta  = (const float*)d_in[15];
  float* out = (float*)d_out;

  char* ws = (char*)d_ws;
  bf16* x_bf    = (bf16*)(ws + 0);          //  8,388,608  (freed after QKV)
  bf16* wqkvT   = (bf16*)(ws + 8388608);    //  6,291,456  (freed after QKV)
  bf16* woT     = (bf16*)(ws + 14680064);   //  2,097,152
  bf16* w1T     = (bf16*)(ws + 16777216);   //  8,388,608
  bf16* w2T     = (bf16*)(ws + 25165824);   //  8,388,608
  float* bqkv   = (float*)(ws + 33554432);  //     12,288
  bf16* qkv     = (bf16*)(ws + 33566720);   // 25,165,824  (q cols only; freed after attn)
  bf16* vB      = (bf16*)(ws + 58732544);   //  8,388,608  (freed after attn)
  bf16* attn    = (bf16*)(ws + 67121152);   //  8,388,608
  bf16* attnout = (bf16*)(ws + 75509760);   //  8,388,608
  bf16* hbuf    = (bf16*)(ws + 92286976);   // 33,554,432
  bf16* kP      = (bf16*)(ws + 92286976);   //  8,388,608 (hbuf head; attn done before W1 writes)
  // W2 split-K=4 bf16 partials in freed regions:
  bf16* P0 = (bf16*)(ws + 0);               // x_bf
  bf16* P1 = (bf16*)(ws + 8388608);         // wqkvT
  bf16* P2 = (bf16*)(ws + 33566720);        // qkv (first 8 MB)
  bf16* P3 = (bf16*)(ws + 41955328);        // qkv (next 8 MB)

  convert_kernel<<<4096, 256, 0, stream>>>(x, (unsigned short*)x_bf, 1048576);
  transpose4_convert<<<dim3(32, 32, 4), 256, 0, stream>>>(
      Wq, Wk, Wv, Wo,
      wqkvT, wqkvT + 1024 * 1024, wqkvT + 2048 * 1024, woT);
  transpose_convert<<<dim3(128, 32), 256, 0, stream>>>(W1, w1T, 1024, 4096);
  transpose_convert<<<dim3(32, 128), 256, 0, stream>>>(W2, w2T, 4096, 1024);
  pack_bias_kernel<<<12, 256, 0, stream>>>(bq, bk, bv, bqkv);

  gemm_bf16<1, 128><<<768, 256, 0, stream>>>(x_bf, wqkvT, bqkv, qkv, kP, vB, nullptr, 4096, 3072, 1024);
  attn_kernel<<<dim3(1024), 256, 0, stream>>>(qkv, kP, vB, attn);
  gemm_bf16<0, 64><<<512, 256, 0, stream>>>(attn, woT, bo, attnout, nullptr, nullptr, nullptr, 4096, 1024, 1024);
  gemm_bf16<2, 128><<<1024, 256, 0, stream>>>(attnout, w1T, b1, hbuf, nullptr, nullptr, nullptr, 4096, 4096, 1024);
  gemm_bf16<3, 128><<<1024, 256, 0, stream>>>(hbuf, w2T, nullptr, nullptr, nullptr, nullptr, ws, 4096, 1024, 4096);
  ln_kernel<<<4096, 256, 0, stream>>>(attnout, P0, P1, P2, P3, b2, gamma, beta, out);
}

// Round 21
// 234.142 us; speedup vs baseline: 1.0658x; 1.0125x over previous
//
#include <hip/hip_runtime.h>
#include <hip/hip_bf16.h>
#include <cmath>
#include <cstdint>

typedef __hip_bfloat16 bf16;
typedef __attribute__((ext_vector_type(4))) float f32x4;
typedef __attribute__((ext_vector_type(16))) float f32x16;
typedef __attribute__((ext_vector_type(8))) short s16x8;
typedef __attribute__((ext_vector_type(4))) unsigned int u32x4;
typedef __attribute__((ext_vector_type(2))) unsigned int u32x2;

#define NB 2
#define NS 2048
#define ND 1024
#define NH 16
#define NHD 64

static __device__ __forceinline__ bf16 f2bf(float v){ return __float2bfloat16(v); }
static __device__ __forceinline__ unsigned short f2bfu(float v){
  bf16 b = __float2bfloat16(v);
  return *reinterpret_cast<unsigned short*>(&b);
}
static __device__ __forceinline__ float bfu2f(unsigned short u){
  union { unsigned int i; float f; } c; c.i = ((unsigned int)u) << 16; return c.f;
}

static __device__ __forceinline__ void gload_lds16(const void* g, void* l){
  __builtin_amdgcn_global_load_lds((const __attribute__((address_space(1))) void*)g,
                                   (__attribute__((address_space(3))) void*)l, 16, 0, 0);
}

// ---------------- prep kernels ----------------

__global__ __launch_bounds__(256) void convert_kernel(const float* __restrict__ src,
                                                       unsigned short* __restrict__ dst, int n4){
  int i = blockIdx.x * 256 + threadIdx.x;
  if (i >= n4) return;
  float4 v = ((const float4*)src)[i];
  ushort4 o;
  o.x = f2bfu(v.x); o.y = f2bfu(v.y); o.z = f2bfu(v.z); o.w = f2bfu(v.w);
  ((ushort4*)dst)[i] = o;
}

// src fp32 [R][C] -> dst bf16 [C][R]
__global__ __launch_bounds__(256) void transpose_convert(const float* __restrict__ src,
                                                          bf16* __restrict__ dst, int R, int C){
  __shared__ float tile[32][33];
  int c0 = blockIdx.x * 32, r0 = blockIdx.y * 32;
  int tx = threadIdx.x & 31, ty = threadIdx.x >> 5;
  #pragma unroll
  for (int i = ty; i < 32; i += 8)
    tile[i][tx] = src[(size_t)(r0 + i) * C + c0 + tx];
  __syncthreads();
  #pragma unroll
  for (int i = ty; i < 32; i += 8)
    dst[(size_t)(c0 + i) * R + r0 + tx] = f2bf(tile[tx][i]);
}

// batched 1024x1024 transpose-convert: z selects {Wq,Wk,Wv,Wo}
__global__ __launch_bounds__(256) void transpose4_convert(
    const float* __restrict__ s0, const float* __restrict__ s1,
    const float* __restrict__ s2, const float* __restrict__ s3,
    bf16* __restrict__ d0, bf16* __restrict__ d1,
    bf16* __restrict__ d2, bf16* __restrict__ d3){
  __shared__ float tile[32][33];
  const int z = blockIdx.z;
  const float* src = (z == 0) ? s0 : (z == 1) ? s1 : (z == 2) ? s2 : s3;
  bf16* dst = (z == 0) ? d0 : (z == 1) ? d1 : (z == 2) ? d2 : d3;
  int c0 = blockIdx.x * 32, r0 = blockIdx.y * 32;
  int tx = threadIdx.x & 31, ty = threadIdx.x >> 5;
  #pragma unroll
  for (int i = ty; i < 32; i += 8)
    tile[i][tx] = src[(size_t)(r0 + i) * 1024 + c0 + tx];
  __syncthreads();
  #pragma unroll
  for (int i = ty; i < 32; i += 8)
    dst[(size_t)(c0 + i) * 1024 + r0 + tx] = f2bf(tile[tx][i]);
}

__global__ void pack_bias_kernel(const float* __restrict__ bq, const float* __restrict__ bk,
                                 const float* __restrict__ bv, float* __restrict__ dst){
  int i = blockIdx.x * 256 + threadIdx.x;
  if (i < 1024) dst[i] = bq[i];
  else if (i < 2048) dst[i] = bk[i - 1024];
  else if (i < 3072) dst[i] = bv[i - 2048];
}

// ------- GEMM: BMxBN tile, BK=64, swizzled staging, single barrier per K-tile -------
// (R14-verified at BN=128; BN=64 adds a 3-blocks/CU variant for tail-free grids)
// 4 waves, 2M x 2N; per-wave out = (BM/2) x (BN/2); NF = BN/32 n-frags.
// EPI: 0 = bias, 1 = QKV (q->qkv, k->kP[bh][s][64], v->vB[bh][t][d][32]),
//      2 = bias+GELU, 3 = split-K=4 bf16 partial (grid 1024: kc=s>>8, no bias)
template<int EPI, int BM, int BN>
__global__ __launch_bounds__(256, (BM == 64 || BN == 64) ? 3 : 2)
void gemm_bf16(const bf16* __restrict__ A, const bf16* __restrict__ BT,
               const float* __restrict__ bias, bf16* __restrict__ C,
               bf16* __restrict__ kP, bf16* __restrict__ vB,
               char* __restrict__ wsbase, int M, int N, int K)
{
  constexpr int MF = BM / 32;                     // m-frags per wave
  constexpr int NF = BN / 32;                     // n-frags per wave
  __shared__ bf16 As[2][BM * 64];
  __shared__ bf16 Bs[2][BN * 64];

  const int tid = threadIdx.x;
  const int lane = tid & 63, wave = tid >> 6;
  const int lr = lane & 15, lg = lane >> 4;
  const int wm = wave >> 1, wn = wave & 1;

  const int nwg = gridDim.x, wg = blockIdx.x;
  const int s = (wg & 7) * (nwg >> 3) + (wg >> 3);   // nwg % 8 == 0 everywhere

  int m0, n0, kbase, NT, ldo;
  bf16* outp;
  if (EPI == 3){
    const int kc = s >> 8, tile = s & 255;        // grid 1024: 4 kc x 256 tiles
    m0 = (tile >> 3) << 7; n0 = (tile & 7) << 7;
    kbase = kc << 10; NT = 16;
    size_t off = (kc < 2) ? (size_t)kc * 8388608u
                          : 33566720u + (size_t)(kc - 2) * 8388608u;
    outp = (bf16*)(wsbase + off); ldo = 1024;
  } else {
    const int nbx = N / BN;
    m0 = (s / nbx) * BM; n0 = (s % nbx) * BN;
    kbase = 0; NT = K >> 6;
    outp = C; ldo = N;
  }

  auto stage = [&](int t, int buf){
    const int k0 = kbase + (t << 6);
    #pragma unroll
    for (int j = 0; j < BM / 32; ++j){            // A: BM*8 16B-units
      const int bi = j * 256 + tid;
      const int row = bi >> 3, slot = bi & 7;
      const int ss = slot ^ (row & 7);
      gload_lds16(A + (size_t)(m0 + row) * K + k0 + ss * 8,
                  (char*)(&As[buf][0]) + bi * 16);
    }
    #pragma unroll
    for (int j = 0; j < BN / 32; ++j){            // B: BN*8 16B-units
      const int bi = j * 256 + tid;
      const int row = bi >> 3, slot = bi & 7;
      const int ss = slot ^ (row & 7);
      gload_lds16(BT + (size_t)(n0 + row) * K + k0 + ss * 8,
                  (char*)(&Bs[buf][0]) + bi * 16);
    }
  };

  f32x4 acc[MF][NF] = {};
  const int rsx = lr & 7;

  stage(0, 0);
  __syncthreads();

  #pragma unroll 1
  for (int G = 0; G < NT; ++G){
    const int X = G & 1;
    if (G + 1 < NT) stage(G + 1, X ^ 1);          // in flight across this tile's compute

    s16x8 bfr[NF][2];
    #pragma unroll
    for (int n = 0; n < NF; ++n){
      const int rowb = wn * (BN / 2) + n * 16 + lr;
      #pragma unroll
      for (int kk = 0; kk < 2; ++kk){
        const int slot = ((kk << 2) + lg) ^ rsx;
        bfr[n][kk] = *(const s16x8*)((const char*)(&Bs[X][0]) + rowb * 128 + slot * 16);
      }
    }
    #pragma unroll
    for (int m = 0; m < MF; ++m){
      s16x8 af[2];
      const int rowa = wm * (BM / 2) + m * 16 + lr;
      #pragma unroll
      for (int kk = 0; kk < 2; ++kk){
        const int slot = ((kk << 2) + lg) ^ rsx;
        af[kk] = *(const s16x8*)((const char*)(&As[X][0]) + rowa * 128 + slot * 16);
      }
      #pragma unroll
      for (int n = 0; n < NF; ++n){
        acc[m][n] = __builtin_amdgcn_mfma_f32_16x16x32_bf16(af[0], bfr[n][0], acc[m][n], 0, 0, 0);
        acc[m][n] = __builtin_amdgcn_mfma_f32_16x16x32_bf16(af[1], bfr[n][1], acc[m][n], 0, 0, 0);
      }
    }
    __syncthreads();                               // single barrier per K-tile
  }

  // ---- epilogue ----
  if (EPI == 1 && n0 >= 2048){
    // V block: packed 8B write into tile-blocked vB[bh][sq>>5][d][sq&31]
    #pragma unroll
    for (int n = 0; n < NF; ++n){
      const int col = n0 + wn * (BN / 2) + n * 16 + lr;
      const float bv = bias[col];
      const int c2 = col - 2048, h = c2 >> 6, d = c2 & 63;
      #pragma unroll
      for (int m = 0; m < MF; ++m){
        const int row = m0 + wm * (BM / 2) + m * 16 + lg * 4;
        const int b = row >> 11, sq = row & 2047;
        unsigned int lo = (unsigned int)f2bfu(acc[m][n][0] + bv) | ((unsigned int)f2bfu(acc[m][n][1] + bv) << 16);
        unsigned int hi2 = (unsigned int)f2bfu(acc[m][n][2] + bv) | ((unsigned int)f2bfu(acc[m][n][3] + bv) << 16);
        u32x2 val; val[0] = lo; val[1] = hi2;
        const size_t idx = (((size_t)(b * NH + h) * 64 + (sq >> 5)) * 64 + d) * 32 + (sq & 31);
        *(u32x2*)&vB[idx] = val;
      }
    }
  } else if (EPI == 1 && n0 >= 1024){
    // K block: scalar writes into packed kP[bh][sq][d] (128B rows)
    #pragma unroll
    for (int n = 0; n < NF; ++n){
      const int col = n0 + wn * (BN / 2) + n * 16 + lr;
      const float bv = bias[col];
      const int c2 = col - 1024, h = c2 >> 6, d = c2 & 63;
      #pragma unroll
      for (int m = 0; m < MF; ++m){
        #pragma unroll
        for (int r = 0; r < 4; ++r){
          const int row = m0 + wm * (BM / 2) + m * 16 + lg * 4 + r;
          const int b = row >> 11, sq = row & 2047;
          kP[((size_t)(b * NH + h) * 2048 + sq) * 64 + d] = f2bf(acc[m][n][r] + bv);
        }
      }
    }
  } else {
    #pragma unroll
    for (int n = 0; n < NF; ++n){
      const int col = n0 + wn * (BN / 2) + n * 16 + lr;
      const float bv = (EPI == 3) ? 0.f : bias[col];
      #pragma unroll
      for (int m = 0; m < MF; ++m){
        #pragma unroll
        for (int r = 0; r < 4; ++r){
          const int row = m0 + wm * (BM / 2) + m * 16 + lg * 4 + r;
          float v = acc[m][n][r] + bv;
          if (EPI == 2) v = 0.5f * v * (1.f + erff(v * 0.70710678118f));
          outp[(size_t)row * ldo + col] = f2bf(v);
        }
      }
    }
  }
}

// ---------------- flash attention (R14-proven: strip-pair blocks, packed K/V) ----------------
// qkv: [4096][3072] bf16 (q cols only), kP: [bh][2048][64], vB: [bh][64][64][32]
// Block = strip-pair (63-p, p) x key-half; 4 waves, ~65 tiles total (uniform), one barrier.
__global__ __launch_bounds__(256, 3)
void attn_kernel(const bf16* __restrict__ qkv, const bf16* __restrict__ kP,
                 const bf16* __restrict__ vB, bf16* __restrict__ out)
{
  const int j = blockIdx.x;
  const int bh = j & 31, p = j >> 5;           // bh -> XCD pinned
  const int b = bh >> 4, h = bh & 15;
  const int tid = threadIdx.x, lane = tid & 63, wave = tid >> 6;
  const int l31 = lane & 31, hi = lane >> 5;
  const int strip = (wave < 2) ? (63 - p) : p;
  const int hsel = wave & 1, sidx = wave >> 1;
  const int q0 = strip * 32;

  __shared__ float Ob[2][32 * 64];
  __shared__ float Lb[2][32];

  auto scale8 = [](s16x8 v){
    s16x8 o;
    #pragma unroll
    for (int i = 0; i < 8; ++i){
      unsigned short u = (unsigned short)v[i];
      unsigned short e = u & 0x7F80;
      o[i] = (short)(e > (3 << 7) ? (unsigned short)(u - (3 << 7)) : (unsigned short)(u & 0x8000));
    }
    return o;
  };

  const bf16* qbase = qkv + (size_t)(b * NS + q0 + l31) * 3072 + h * 64 + hi * 8;
  s16x8 qf[4];
  #pragma unroll
  for (int kk = 0; kk < 4; ++kk)
    qf[kk] = scale8(*(const s16x8*)(qbase + kk * 16));

  const bf16* kpb = kP + (size_t)bh * 2048 * 64;
  const bf16* vbb = vB + (size_t)bh * 64 * 64 * 32;

  f32x16 oacc0 = {}, oacc1 = {};
  float lsum = 0.f;

  #pragma unroll 1
  for (int t = hsel; t <= strip; t += 2){
    const bf16* krow = kpb + (size_t)(t * 32 + l31) * 64 + hi * 8;
    s16x8 kf0 = *(const s16x8*)(krow);
    s16x8 kf1 = *(const s16x8*)(krow + 16);
    s16x8 kf2 = *(const s16x8*)(krow + 32);
    s16x8 kf3 = *(const s16x8*)(krow + 48);
    const bf16* vt0 = vbb + ((size_t)t * 64 + l31) * 32 + hi * 8;
    const bf16* vt1 = vbb + ((size_t)t * 64 + 32 + l31) * 32 + hi * 8;
    s16x8 vf00 = *(const s16x8*)(vt0);
    s16x8 vf10 = *(const s16x8*)(vt0 + 16);
    s16x8 vf01 = *(const s16x8*)(vt1);
    s16x8 vf11 = *(const s16x8*)(vt1 + 16);

    f32x16 sacc = {};
    sacc = __builtin_amdgcn_mfma_f32_32x32x16_bf16(kf0, qf[0], sacc, 0, 0, 0);
    sacc = __builtin_amdgcn_mfma_f32_32x32x16_bf16(kf1, qf[1], sacc, 0, 0, 0);
    sacc = __builtin_amdgcn_mfma_f32_32x32x16_bf16(kf2, qf[2], sacc, 0, 0, 0);
    sacc = __builtin_amdgcn_mfma_f32_32x32x16_bf16(kf3, qf[3], sacc, 0, 0, 0);

    const bool dg = (t == strip);
    float pv[16];
    #pragma unroll
    for (int r = 0; r < 16; ++r){
      const int kloc = (r & 3) + 8 * (r >> 2) + 4 * hi;
      float e = __expf(sacc[r]);
      if (dg && kloc > l31) e = 0.f;
      pv[r] = e;
      lsum += e;
    }
    unsigned int w[8];
    #pragma unroll
    for (int i = 0; i < 8; ++i)
      w[i] = (unsigned int)f2bfu(pv[2 * i]) | ((unsigned int)f2bfu(pv[2 * i + 1]) << 16);
    unsigned int s0 = hi ? w[0] : w[2];
    unsigned int s1 = hi ? w[1] : w[3];
    unsigned int s2 = hi ? w[4] : w[6];
    unsigned int s3 = hi ? w[5] : w[7];
    unsigned int g0 = (unsigned int)__shfl_xor((int)s0, 32);
    unsigned int g1 = (unsigned int)__shfl_xor((int)s1, 32);
    unsigned int g2 = (unsigned int)__shfl_xor((int)s2, 32);
    unsigned int g3 = (unsigned int)__shfl_xor((int)s3, 32);
    union { u32x4 u; s16x8 s; } pa0, pa1;
    if (hi == 0){
      pa0.u[0] = w[0]; pa0.u[1] = w[1]; pa0.u[2] = g0; pa0.u[3] = g1;
      pa1.u[0] = w[4]; pa1.u[1] = w[5]; pa1.u[2] = g2; pa1.u[3] = g3;
    } else {
      pa0.u[0] = g0; pa0.u[1] = g1; pa0.u[2] = w[2]; pa0.u[3] = w[3];
      pa1.u[0] = g2; pa1.u[1] = g3; pa1.u[2] = w[6]; pa1.u[3] = w[7];
    }
    oacc0 = __builtin_amdgcn_mfma_f32_32x32x16_bf16(pa0.s, vf00, oacc0, 0, 0, 0);
    oacc0 = __builtin_amdgcn_mfma_f32_32x32x16_bf16(pa1.s, vf10, oacc0, 0, 0, 0);
    oacc1 = __builtin_amdgcn_mfma_f32_32x32x16_bf16(pa0.s, vf01, oacc1, 0, 0, 0);
    oacc1 = __builtin_amdgcn_mfma_f32_32x32x16_bf16(pa1.s, vf11, oacc1, 0, 0, 0);
  }

  lsum += __shfl_xor(lsum, 32);
  if (hsel == 0){
    #pragma unroll
    for (int r = 0; r < 16; ++r){
      const int rowq = (r & 3) + 8 * (r >> 2) + 4 * hi;
      Ob[sidx][rowq * 64 + l31] = oacc0[r];
      Ob[sidx][rowq * 64 + 32 + l31] = oacc1[r];
    }
    if (hi == 0) Lb[sidx][l31] = lsum;
    __syncthreads();
  } else {
    __syncthreads();
    float lf = lsum + Lb[sidx][l31];
    if (hi == 0) Lb[sidx][l31] = lf;
    #pragma unroll
    for (int r = 0; r < 16; ++r){
      const int rowq = (r & 3) + 8 * (r >> 2) + 4 * hi;
      const float denom = Lb[sidx][rowq];
      const float o0 = oacc0[r] + Ob[sidx][rowq * 64 + l31];
      const float o1 = oacc1[r] + Ob[sidx][rowq * 64 + 32 + l31];
      const size_t rbase = (size_t)(b * NS + q0 + rowq) * ND + h * 64;
      out[rbase + l31] = f2bf(o0 / denom);
      out[rbase + 32 + l31] = f2bf(o1 / denom);
    }
  }
}

// ---------------- residual + 4-partial combine + b2 + LayerNorm ----------------
__global__ __launch_bounds__(256)
void ln_kernel(const bf16* __restrict__ a, const bf16* __restrict__ p0,
               const bf16* __restrict__ p1, const bf16* __restrict__ p2,
               const bf16* __restrict__ p3, const float* __restrict__ badd,
               const float* __restrict__ gamma, const float* __restrict__ beta,
               float* __restrict__ out)
{
  const int row = blockIdx.x;
  const int tid = threadIdx.x;
  const int lane = tid & 63, wave = tid >> 6;
  const size_t base = (size_t)row * ND;
  ushort4 ua = *(const ushort4*)((const unsigned short*)a  + base + tid * 4);
  ushort4 u0 = *(const ushort4*)((const unsigned short*)p0 + base + tid * 4);
  ushort4 u1 = *(const ushort4*)((const unsigned short*)p1 + base + tid * 4);
  ushort4 u2 = *(const ushort4*)((const unsigned short*)p2 + base + tid * 4);
  ushort4 u3 = *(const ushort4*)((const unsigned short*)p3 + base + tid * 4);
  float4 vb = *(const float4*)(badd + tid * 4);
  float y[4];
  y[0] = bfu2f(ua.x) + bfu2f(u0.x) + bfu2f(u1.x) + bfu2f(u2.x) + bfu2f(u3.x) + vb.x;
  y[1] = bfu2f(ua.y) + bfu2f(u0.y) + bfu2f(u1.y) + bfu2f(u2.y) + bfu2f(u3.y) + vb.y;
  y[2] = bfu2f(ua.z) + bfu2f(u0.z) + bfu2f(u1.z) + bfu2f(u2.z) + bfu2f(u3.z) + vb.z;
  y[3] = bfu2f(ua.w) + bfu2f(u0.w) + bfu2f(u1.w) + bfu2f(u2.w) + bfu2f(u3.w) + vb.w;
  float s = y[0] + y[1] + y[2] + y[3];
  float ss = y[0]*y[0] + y[1]*y[1] + y[2]*y[2] + y[3]*y[3];
  #pragma unroll
  for (int off = 1; off < 64; off <<= 1){
    s  += __shfl_xor(s, off);
    ss += __shfl_xor(ss, off);
  }
  __shared__ float rs[4], rss[4];
  if (lane == 0){ rs[wave] = s; rss[wave] = ss; }
  __syncthreads();
  const float S  = rs[0] + rs[1] + rs[2] + rs[3];
  const float SS = rss[0] + rss[1] + rss[2] + rss[3];
  const float mu = S * (1.f / 1024.f);
  const float var = SS * (1.f / 1024.f) - mu * mu;
  const float inv = rsqrtf(var + 1e-6f);
  #pragma unroll
  for (int jj = 0; jj < 4; ++jj){
    int c = tid * 4 + jj;
    out[base + c] = (y[jj] - mu) * inv * gamma[c] + beta[c];
  }
}

// ---------------- launcher ----------------
extern "C" void kernel_launch(void* const* d_in, const int* in_sizes, int n_in,
                              void* d_out, int out_size, void* d_ws, size_t ws_size,
                              hipStream_t stream)
{
  (void)in_sizes; (void)n_in; (void)out_size; (void)ws_size;
  const float* x  = (const float*)d_in[0];
  const float* Wq = (const float*)d_in[2];
  const float* bq = (const float*)d_in[3];
  const float* Wk = (const float*)d_in[4];
  const float* bk = (const float*)d_in[5];
  const float* Wv = (const float*)d_in[6];
  const float* bv = (const float*)d_in[7];
  const float* Wo = (const float*)d_in[8];
  const float* bo = (const float*)d_in[9];
  const float* W1 = (const float*)d_in[10];
  const float* b1 = (const float*)d_in[11];
  const float* W2 = (const float*)d_in[12];
  const float* b2 = (const float*)d_in[13];
  const float* gamma = (const float*)d_in[14];
  const float* beta  = (const float*)d_in[15];
  float* out = (float*)d_out;

  char* ws = (char*)d_ws;
  bf16* x_bf    = (bf16*)(ws + 0);          //  8,388,608  (freed after QKV)
  bf16* wqkvT   = (bf16*)(ws + 8388608);    //  6,291,456  (freed after QKV)
  bf16* woT     = (bf16*)(ws + 14680064);   //  2,097,152
  bf16* w1T     = (bf16*)(ws + 16777216);   //  8,388,608
  bf16* w2T     = (bf16*)(ws + 25165824);   //  8,388,608
  float* bqkv   = (float*)(ws + 33554432);  //     12,288
  bf16* qkv     = (bf16*)(ws + 33566720);   // 25,165,824  (q cols only; freed after attn)
  bf16* vB      = (bf16*)(ws + 58732544);   //  8,388,608  (freed after attn)
  bf16* attn    = (bf16*)(ws + 67121152);   //  8,388,608
  bf16* attnout = (bf16*)(ws + 75509760);   //  8,388,608
  bf16* hbuf    = (bf16*)(ws + 92286976);   // 33,554,432
  bf16* kP      = (bf16*)(ws + 92286976);   //  8,388,608 (hbuf head; attn done before W1 writes)
  // W2 split-K=4 bf16 partials in freed regions:
  bf16* P0 = (bf16*)(ws + 0);               // x_bf
  bf16* P1 = (bf16*)(ws + 8388608);         // wqkvT
  bf16* P2 = (bf16*)(ws + 33566720);        // qkv (first 8 MB)
  bf16* P3 = (bf16*)(ws + 41955328);        // qkv (next 8 MB)

  convert_kernel<<<4096, 256, 0, stream>>>(x, (unsigned short*)x_bf, 1048576);
  transpose4_convert<<<dim3(32, 32, 4), 256, 0, stream>>>(
      Wq, Wk, Wv, Wo,
      wqkvT, wqkvT + 1024 * 1024, wqkvT + 2048 * 1024, woT);
  transpose_convert<<<dim3(128, 32), 256, 0, stream>>>(W1, w1T, 1024, 4096);
  transpose_convert<<<dim3(32, 128), 256, 0, stream>>>(W2, w2T, 4096, 1024);
  pack_bias_kernel<<<12, 256, 0, stream>>>(bq, bk, bv, bqkv);

  gemm_bf16<1, 128, 64><<<1536, 256, 0, stream>>>(x_bf, wqkvT, bqkv, qkv, kP, vB, nullptr, 4096, 3072, 1024);
  attn_kernel<<<dim3(1024), 256, 0, stream>>>(qkv, kP, vB, attn);
  gemm_bf16<0, 64, 128><<<512, 256, 0, stream>>>(attn, woT, bo, attnout, nullptr, nullptr, nullptr, 4096, 1024, 1024);
  gemm_bf16<2, 128, 128><<<1024, 256, 0, stream>>>(attnout, w1T, b1, hbuf, nullptr, nullptr, nullptr, 4096, 4096, 1024);
  gemm_bf16<3, 128, 128><<<1024, 256, 0, stream>>>(hbuf, w2T, nullptr, nullptr, nullptr, nullptr, ws, 4096, 1024, 4096);
  ln_kernel<<<4096, 256, 0, stream>>>(attnout, P0, P1, P2, P3, b2, gamma, beta, out);
}

// Round 22
// 229.838 us; speedup vs baseline: 1.0857x; 1.0187x over previous
//
#include <hip/hip_runtime.h>
#include <hip/hip_bf16.h>
#include <cmath>
#include <cstdint>

typedef __hip_bfloat16 bf16;
typedef __attribute__((ext_vector_type(4))) float f32x4;
typedef __attribute__((ext_vector_type(16))) float f32x16;
typedef __attribute__((ext_vector_type(8))) short s16x8;
typedef __attribute__((ext_vector_type(4))) unsigned int u32x4;
typedef __attribute__((ext_vector_type(2))) unsigned int u32x2;

#define NB 2
#define NS 2048
#define ND 1024
#define NH 16
#define NHD 64

static __device__ __forceinline__ bf16 f2bf(float v){ return __float2bfloat16(v); }
static __device__ __forceinline__ unsigned short f2bfu(float v){
  bf16 b = __float2bfloat16(v);
  return *reinterpret_cast<unsigned short*>(&b);
}
static __device__ __forceinline__ float bfu2f(unsigned short u){
  union { unsigned int i; float f; } c; c.i = ((unsigned int)u) << 16; return c.f;
}

static __device__ __forceinline__ void gload_lds16(const void* g, void* l){
  __builtin_amdgcn_global_load_lds((const __attribute__((address_space(1))) void*)g,
                                   (__attribute__((address_space(3))) void*)l, 16, 0, 0);
}

// ---------------- prep kernels ----------------

__global__ __launch_bounds__(256) void convert_kernel(const float* __restrict__ src,
                                                       unsigned short* __restrict__ dst, int n4){
  int i = blockIdx.x * 256 + threadIdx.x;
  if (i >= n4) return;
  float4 v = ((const float4*)src)[i];
  ushort4 o;
  o.x = f2bfu(v.x); o.y = f2bfu(v.y); o.z = f2bfu(v.z); o.w = f2bfu(v.w);
  ((ushort4*)dst)[i] = o;
}

// src fp32 [R][C] -> dst bf16 [C][R]
__global__ __launch_bounds__(256) void transpose_convert(const float* __restrict__ src,
                                                          bf16* __restrict__ dst, int R, int C){
  __shared__ float tile[32][33];
  int c0 = blockIdx.x * 32, r0 = blockIdx.y * 32;
  int tx = threadIdx.x & 31, ty = threadIdx.x >> 5;
  #pragma unroll
  for (int i = ty; i < 32; i += 8)
    tile[i][tx] = src[(size_t)(r0 + i) * C + c0 + tx];
  __syncthreads();
  #pragma unroll
  for (int i = ty; i < 32; i += 8)
    dst[(size_t)(c0 + i) * R + r0 + tx] = f2bf(tile[tx][i]);
}

// batched 1024x1024 transpose-convert: z selects {Wq,Wk,Wv,Wo}
__global__ __launch_bounds__(256) void transpose4_convert(
    const float* __restrict__ s0, const float* __restrict__ s1,
    const float* __restrict__ s2, const float* __restrict__ s3,
    bf16* __restrict__ d0, bf16* __restrict__ d1,
    bf16* __restrict__ d2, bf16* __restrict__ d3){
  __shared__ float tile[32][33];
  const int z = blockIdx.z;
  const float* src = (z == 0) ? s0 : (z == 1) ? s1 : (z == 2) ? s2 : s3;
  bf16* dst = (z == 0) ? d0 : (z == 1) ? d1 : (z == 2) ? d2 : d3;
  int c0 = blockIdx.x * 32, r0 = blockIdx.y * 32;
  int tx = threadIdx.x & 31, ty = threadIdx.x >> 5;
  #pragma unroll
  for (int i = ty; i < 32; i += 8)
    tile[i][tx] = src[(size_t)(r0 + i) * 1024 + c0 + tx];
  __syncthreads();
  #pragma unroll
  for (int i = ty; i < 32; i += 8)
    dst[(size_t)(c0 + i) * 1024 + r0 + tx] = f2bf(tile[tx][i]);
}

__global__ void pack_bias_kernel(const float* __restrict__ bq, const float* __restrict__ bk,
                                 const float* __restrict__ bv, float* __restrict__ dst){
  int i = blockIdx.x * 256 + threadIdx.x;
  if (i < 1024) dst[i] = bq[i];
  else if (i < 2048) dst[i] = bk[i - 1024];
  else if (i < 3072) dst[i] = bv[i - 2048];
}

// ------- GEMM: BMxBN tile, BK=64, swizzled staging, single barrier per K-tile -------
// (R14-verified at BN=128; BN=64 3-blocks/CU variant for tail-free grids, R21)
// EPI: 0 = bias, 1 = QKV (q->qkv, k->kP[bh][s][64], v->vB[bh][t][d][32]),
//      2 = bias+GELU, 3 = split-K=2 bf16 partial (grid 512: kc=s>>8, K window kc*2048)
template<int EPI, int BM, int BN>
__global__ __launch_bounds__(256, (BM == 64 || BN == 64) ? 3 : 2)
void gemm_bf16(const bf16* __restrict__ A, const bf16* __restrict__ BT,
               const float* __restrict__ bias, bf16* __restrict__ C,
               bf16* __restrict__ kP, bf16* __restrict__ vB,
               char* __restrict__ wsbase, int M, int N, int K)
{
  constexpr int MF = BM / 32;                     // m-frags per wave
  constexpr int NF = BN / 32;                     // n-frags per wave
  __shared__ bf16 As[2][BM * 64];
  __shared__ bf16 Bs[2][BN * 64];

  const int tid = threadIdx.x;
  const int lane = tid & 63, wave = tid >> 6;
  const int lr = lane & 15, lg = lane >> 4;
  const int wm = wave >> 1, wn = wave & 1;

  const int nwg = gridDim.x, wg = blockIdx.x;
  const int s = (wg & 7) * (nwg >> 3) + (wg >> 3);   // nwg % 8 == 0 everywhere

  int m0, n0, kbase, NT, ldo;
  bf16* outp;
  if (EPI == 3){
    const int kc = s >> 8, tile = s & 255;        // grid 512: kc 0..1, 256 tiles
    m0 = (tile >> 3) << 7; n0 = (tile & 7) << 7;
    kbase = kc << 11; NT = 32;
    size_t off = (kc == 0) ? 0u : 8388608u;
    outp = (bf16*)(wsbase + off); ldo = 1024;
  } else {
    const int nbx = N / BN;
    m0 = (s / nbx) * BM; n0 = (s % nbx) * BN;
    kbase = 0; NT = K >> 6;
    outp = C; ldo = N;
  }

  auto stage = [&](int t, int buf){
    const int k0 = kbase + (t << 6);
    #pragma unroll
    for (int j = 0; j < BM / 32; ++j){            // A: BM*8 16B-units
      const int bi = j * 256 + tid;
      const int row = bi >> 3, slot = bi & 7;
      const int ss = slot ^ (row & 7);
      gload_lds16(A + (size_t)(m0 + row) * K + k0 + ss * 8,
                  (char*)(&As[buf][0]) + bi * 16);
    }
    #pragma unroll
    for (int j = 0; j < BN / 32; ++j){            // B: BN*8 16B-units
      const int bi = j * 256 + tid;
      const int row = bi >> 3, slot = bi & 7;
      const int ss = slot ^ (row & 7);
      gload_lds16(BT + (size_t)(n0 + row) * K + k0 + ss * 8,
                  (char*)(&Bs[buf][0]) + bi * 16);
    }
  };

  f32x4 acc[MF][NF] = {};
  const int rsx = lr & 7;

  stage(0, 0);
  __syncthreads();

  #pragma unroll 1
  for (int G = 0; G < NT; ++G){
    const int X = G & 1;
    if (G + 1 < NT) stage(G + 1, X ^ 1);          // in flight across this tile's compute

    s16x8 bfr[NF][2];
    #pragma unroll
    for (int n = 0; n < NF; ++n){
      const int rowb = wn * (BN / 2) + n * 16 + lr;
      #pragma unroll
      for (int kk = 0; kk < 2; ++kk){
        const int slot = ((kk << 2) + lg) ^ rsx;
        bfr[n][kk] = *(const s16x8*)((const char*)(&Bs[X][0]) + rowb * 128 + slot * 16);
      }
    }
    #pragma unroll
    for (int m = 0; m < MF; ++m){
      s16x8 af[2];
      const int rowa = wm * (BM / 2) + m * 16 + lr;
      #pragma unroll
      for (int kk = 0; kk < 2; ++kk){
        const int slot = ((kk << 2) + lg) ^ rsx;
        af[kk] = *(const s16x8*)((const char*)(&As[X][0]) + rowa * 128 + slot * 16);
      }
      #pragma unroll
      for (int n = 0; n < NF; ++n){
        acc[m][n] = __builtin_amdgcn_mfma_f32_16x16x32_bf16(af[0], bfr[n][0], acc[m][n], 0, 0, 0);
        acc[m][n] = __builtin_amdgcn_mfma_f32_16x16x32_bf16(af[1], bfr[n][1], acc[m][n], 0, 0, 0);
      }
    }
    __syncthreads();                               // single barrier per K-tile
  }

  // ---- epilogue ----
  if (EPI == 1 && n0 >= 2048){
    // V block: packed 8B write into tile-blocked vB[bh][sq>>5][d][sq&31]
    #pragma unroll
    for (int n = 0; n < NF; ++n){
      const int col = n0 + wn * (BN / 2) + n * 16 + lr;
      const float bv = bias[col];
      const int c2 = col - 2048, h = c2 >> 6, d = c2 & 63;
      #pragma unroll
      for (int m = 0; m < MF; ++m){
        const int row = m0 + wm * (BM / 2) + m * 16 + lg * 4;
        const int b = row >> 11, sq = row & 2047;
        unsigned int lo = (unsigned int)f2bfu(acc[m][n][0] + bv) | ((unsigned int)f2bfu(acc[m][n][1] + bv) << 16);
        unsigned int hi2 = (unsigned int)f2bfu(acc[m][n][2] + bv) | ((unsigned int)f2bfu(acc[m][n][3] + bv) << 16);
        u32x2 val; val[0] = lo; val[1] = hi2;
        const size_t idx = (((size_t)(b * NH + h) * 64 + (sq >> 5)) * 64 + d) * 32 + (sq & 31);
        *(u32x2*)&vB[idx] = val;
      }
    }
  } else if (EPI == 1 && n0 >= 1024){
    // K block: scalar writes into packed kP[bh][sq][d] (128B rows)
    #pragma unroll
    for (int n = 0; n < NF; ++n){
      const int col = n0 + wn * (BN / 2) + n * 16 + lr;
      const float bv = bias[col];
      const int c2 = col - 1024, h = c2 >> 6, d = c2 & 63;
      #pragma unroll
      for (int m = 0; m < MF; ++m){
        #pragma unroll
        for (int r = 0; r < 4; ++r){
          const int row = m0 + wm * (BM / 2) + m * 16 + lg * 4 + r;
          const int b = row >> 11, sq = row & 2047;
          kP[((size_t)(b * NH + h) * 2048 + sq) * 64 + d] = f2bf(acc[m][n][r] + bv);
        }
      }
    }
  } else {
    #pragma unroll
    for (int n = 0; n < NF; ++n){
      const int col = n0 + wn * (BN / 2) + n * 16 + lr;
      const float bv = (EPI == 3) ? 0.f : bias[col];
      #pragma unroll
      for (int m = 0; m < MF; ++m){
        #pragma unroll
        for (int r = 0; r < 4; ++r){
          const int row = m0 + wm * (BM / 2) + m * 16 + lg * 4 + r;
          float v = acc[m][n][r] + bv;
          if (EPI == 2) v = 0.5f * v * (1.f + erff(v * 0.70710678118f));
          outp[(size_t)row * ldo + col] = f2bf(v);
        }
      }
    }
  }
}

// ---------------- flash attention (R14-proven: strip-pair blocks, packed K/V) ----------------
__global__ __launch_bounds__(256, 3)
void attn_kernel(const bf16* __restrict__ qkv, const bf16* __restrict__ kP,
                 const bf16* __restrict__ vB, bf16* __restrict__ out)
{
  const int j = blockIdx.x;
  const int bh = j & 31, p = j >> 5;           // bh -> XCD pinned
  const int b = bh >> 4, h = bh & 15;
  const int tid = threadIdx.x, lane = tid & 63, wave = tid >> 6;
  const int l31 = lane & 31, hi = lane >> 5;
  const int strip = (wave < 2) ? (63 - p) : p;
  const int hsel = wave & 1, sidx = wave >> 1;
  const int q0 = strip * 32;

  __shared__ float Ob[2][32 * 64];
  __shared__ float Lb[2][32];

  auto scale8 = [](s16x8 v){
    s16x8 o;
    #pragma unroll
    for (int i = 0; i < 8; ++i){
      unsigned short u = (unsigned short)v[i];
      unsigned short e = u & 0x7F80;
      o[i] = (short)(e > (3 << 7) ? (unsigned short)(u - (3 << 7)) : (unsigned short)(u & 0x8000));
    }
    return o;
  };

  const bf16* qbase = qkv + (size_t)(b * NS + q0 + l31) * 3072 + h * 64 + hi * 8;
  s16x8 qf[4];
  #pragma unroll
  for (int kk = 0; kk < 4; ++kk)
    qf[kk] = scale8(*(const s16x8*)(qbase + kk * 16));

  const bf16* kpb = kP + (size_t)bh * 2048 * 64;
  const bf16* vbb = vB + (size_t)bh * 64 * 64 * 32;

  f32x16 oacc0 = {}, oacc1 = {};
  float lsum = 0.f;

  #pragma unroll 1
  for (int t = hsel; t <= strip; t += 2){
    const bf16* krow = kpb + (size_t)(t * 32 + l31) * 64 + hi * 8;
    s16x8 kf0 = *(const s16x8*)(krow);
    s16x8 kf1 = *(const s16x8*)(krow + 16);
    s16x8 kf2 = *(const s16x8*)(krow + 32);
    s16x8 kf3 = *(const s16x8*)(krow + 48);
    const bf16* vt0 = vbb + ((size_t)t * 64 + l31) * 32 + hi * 8;
    const bf16* vt1 = vbb + ((size_t)t * 64 + 32 + l31) * 32 + hi * 8;
    s16x8 vf00 = *(const s16x8*)(vt0);
    s16x8 vf10 = *(const s16x8*)(vt0 + 16);
    s16x8 vf01 = *(const s16x8*)(vt1);
    s16x8 vf11 = *(const s16x8*)(vt1 + 16);

    f32x16 sacc = {};
    sacc = __builtin_amdgcn_mfma_f32_32x32x16_bf16(kf0, qf[0], sacc, 0, 0, 0);
    sacc = __builtin_amdgcn_mfma_f32_32x32x16_bf16(kf1, qf[1], sacc, 0, 0, 0);
    sacc = __builtin_amdgcn_mfma_f32_32x32x16_bf16(kf2, qf[2], sacc, 0, 0, 0);
    sacc = __builtin_amdgcn_mfma_f32_32x32x16_bf16(kf3, qf[3], sacc, 0, 0, 0);

    const bool dg = (t == strip);
    float pv[16];
    #pragma unroll
    for (int r = 0; r < 16; ++r){
      const int kloc = (r & 3) + 8 * (r >> 2) + 4 * hi;
      float e = __expf(sacc[r]);
      if (dg && kloc > l31) e = 0.f;
      pv[r] = e;
      lsum += e;
    }
    unsigned int w[8];
    #pragma unroll
    for (int i = 0; i < 8; ++i)
      w[i] = (unsigned int)f2bfu(pv[2 * i]) | ((unsigned int)f2bfu(pv[2 * i + 1]) << 16);
    unsigned int s0 = hi ? w[0] : w[2];
    unsigned int s1 = hi ? w[1] : w[3];
    unsigned int s2 = hi ? w[4] : w[6];
    unsigned int s3 = hi ? w[5] : w[7];
    unsigned int g0 = (unsigned int)__shfl_xor((int)s0, 32);
    unsigned int g1 = (unsigned int)__shfl_xor((int)s1, 32);
    unsigned int g2 = (unsigned int)__shfl_xor((int)s2, 32);
    unsigned int g3 = (unsigned int)__shfl_xor((int)s3, 32);
    union { u32x4 u; s16x8 s; } pa0, pa1;
    if (hi == 0){
      pa0.u[0] = w[0]; pa0.u[1] = w[1]; pa0.u[2] = g0; pa0.u[3] = g1;
      pa1.u[0] = w[4]; pa1.u[1] = w[5]; pa1.u[2] = g2; pa1.u[3] = g3;
    } else {
      pa0.u[0] = g0; pa0.u[1] = g1; pa0.u[2] = w[2]; pa0.u[3] = w[3];
      pa1.u[0] = g2; pa1.u[1] = g3; pa1.u[2] = w[6]; pa1.u[3] = w[7];
    }
    oacc0 = __builtin_amdgcn_mfma_f32_32x32x16_bf16(pa0.s, vf00, oacc0, 0, 0, 0);
    oacc0 = __builtin_amdgcn_mfma_f32_32x32x16_bf16(pa1.s, vf10, oacc0, 0, 0, 0);
    oacc1 = __builtin_amdgcn_mfma_f32_32x32x16_bf16(pa0.s, vf01, oacc1, 0, 0, 0);
    oacc1 = __builtin_amdgcn_mfma_f32_32x32x16_bf16(pa1.s, vf11, oacc1, 0, 0, 0);
  }

  lsum += __shfl_xor(lsum, 32);
  if (hsel == 0){
    #pragma unroll
    for (int r = 0; r < 16; ++r){
      const int rowq = (r & 3) + 8 * (r >> 2) + 4 * hi;
      Ob[sidx][rowq * 64 + l31] = oacc0[r];
      Ob[sidx][rowq * 64 + 32 + l31] = oacc1[r];
    }
    if (hi == 0) Lb[sidx][l31] = lsum;
    __syncthreads();
  } else {
    __syncthreads();
    float lf = lsum + Lb[sidx][l31];
    if (hi == 0) Lb[sidx][l31] = lf;
    #pragma unroll
    for (int r = 0; r < 16; ++r){
      const int rowq = (r & 3) + 8 * (r >> 2) + 4 * hi;
      const float denom = Lb[sidx][rowq];
      const float o0 = oacc0[r] + Ob[sidx][rowq * 64 + l31];
      const float o1 = oacc1[r] + Ob[sidx][rowq * 64 + 32 + l31];
      const size_t rbase = (size_t)(b * NS + q0 + rowq) * ND + h * 64;
      out[rbase + l31] = f2bf(o0 / denom);
      out[rbase + 32 + l31] = f2bf(o1 / denom);
    }
  }
}

// ---------------- residual + 2-partial combine + b2 + LayerNorm ----------------
__global__ __launch_bounds__(256)
void ln_kernel(const bf16* __restrict__ a, const bf16* __restrict__ p0,
               const bf16* __restrict__ p1, const float* __restrict__ badd,
               const float* __restrict__ gamma, const float* __restrict__ beta,
               float* __restrict__ out)
{
  const int row = blockIdx.x;
  const int tid = threadIdx.x;
  const int lane = tid & 63, wave = tid >> 6;
  const size_t base = (size_t)row * ND;
  ushort4 ua = *(const ushort4*)((const unsigned short*)a  + base + tid * 4);
  ushort4 u0 = *(const ushort4*)((const unsigned short*)p0 + base + tid * 4);
  ushort4 u1 = *(const ushort4*)((const unsigned short*)p1 + base + tid * 4);
  float4 vb = *(const float4*)(badd + tid * 4);
  float y[4];
  y[0] = bfu2f(ua.x) + bfu2f(u0.x) + bfu2f(u1.x) + vb.x;
  y[1] = bfu2f(ua.y) + bfu2f(u0.y) + bfu2f(u1.y) + vb.y;
  y[2] = bfu2f(ua.z) + bfu2f(u0.z) + bfu2f(u1.z) + vb.z;
  y[3] = bfu2f(ua.w) + bfu2f(u0.w) + bfu2f(u1.w) + vb.w;
  float s = y[0] + y[1] + y[2] + y[3];
  float ss = y[0]*y[0] + y[1]*y[1] + y[2]*y[2] + y[3]*y[3];
  #pragma unroll
  for (int off = 1; off < 64; off <<= 1){
    s  += __shfl_xor(s, off);
    ss += __shfl_xor(ss, off);
  }
  __shared__ float rs[4], rss[4];
  if (lane == 0){ rs[wave] = s; rss[wave] = ss; }
  __syncthreads();
  const float S  = rs[0] + rs[1] + rs[2] + rs[3];
  const float SS = rss[0] + rss[1] + rss[2] + rss[3];
  const float mu = S * (1.f / 1024.f);
  const float var = SS * (1.f / 1024.f) - mu * mu;
  const float inv = rsqrtf(var + 1e-6f);
  #pragma unroll
  for (int jj = 0; jj < 4; ++jj){
    int c = tid * 4 + jj;
    out[base + c] = (y[jj] - mu) * inv * gamma[c] + beta[c];
  }
}

// ---------------- launcher ----------------
extern "C" void kernel_launch(void* const* d_in, const int* in_sizes, int n_in,
                              void* d_out, int out_size, void* d_ws, size_t ws_size,
                              hipStream_t stream)
{
  (void)in_sizes; (void)n_in; (void)out_size; (void)ws_size;
  const float* x  = (const float*)d_in[0];
  const float* Wq = (const float*)d_in[2];
  const float* bq = (const float*)d_in[3];
  const float* Wk = (const float*)d_in[4];
  const float* bk = (const float*)d_in[5];
  const float* Wv = (const float*)d_in[6];
  const float* bv = (const float*)d_in[7];
  const float* Wo = (const float*)d_in[8];
  const float* bo = (const float*)d_in[9];
  const float* W1 = (const float*)d_in[10];
  const float* b1 = (const float*)d_in[11];
  const float* W2 = (const float*)d_in[12];
  const float* b2 = (const float*)d_in[13];
  const float* gamma = (const float*)d_in[14];
  const float* beta  = (const float*)d_in[15];
  float* out = (float*)d_out;

  char* ws = (char*)d_ws;
  bf16* x_bf    = (bf16*)(ws + 0);          //  8,388,608  (freed after QKV)
  bf16* wqkvT   = (bf16*)(ws + 8388608);    //  6,291,456  (freed after QKV)
  bf16* woT     = (bf16*)(ws + 14680064);   //  2,097,152  (freed after Wo)
  bf16* w1T     = (bf16*)(ws + 16777216);   //  8,388,608
  bf16* w2T     = (bf16*)(ws + 25165824);   //  8,388,608
  float* bqkv   = (float*)(ws + 33554432);  //     12,288
  bf16* qkv     = (bf16*)(ws + 33566720);   // 25,165,824  (q cols only; freed after attn)
  bf16* vB      = (bf16*)(ws + 58732544);   //  8,388,608  (freed after attn)
  bf16* attn    = (bf16*)(ws + 67121152);   //  8,388,608
  bf16* attnout = (bf16*)(ws + 75509760);   //  8,388,608
  bf16* hbuf    = (bf16*)(ws + 92286976);   // 33,554,432
  bf16* kP      = (bf16*)(ws + 92286976);   //  8,388,608 (hbuf head; attn done before W1 writes)
  // W2 split-K=2 bf16 partials (8,388,608 B each) in freed regions:
  bf16* P0 = (bf16*)(ws + 0);               // x_bf
  bf16* P1 = (bf16*)(ws + 8388608);         // wqkvT + woT

  convert_kernel<<<4096, 256, 0, stream>>>(x, (unsigned short*)x_bf, 1048576);
  transpose4_convert<<<dim3(32, 32, 4), 256, 0, stream>>>(
      Wq, Wk, Wv, Wo,
      wqkvT, wqkvT + 1024 * 1024, wqkvT + 2048 * 1024, woT);
  transpose_convert<<<dim3(128, 32), 256, 0, stream>>>(W1, w1T, 1024, 4096);
  transpose_convert<<<dim3(32, 128), 256, 0, stream>>>(W2, w2T, 4096, 1024);
  pack_bias_kernel<<<12, 256, 0, stream>>>(bq, bk, bv, bqkv);

  gemm_bf16<1, 128, 64><<<1536, 256, 0, stream>>>(x_bf, wqkvT, bqkv, qkv, kP, vB, nullptr, 4096, 3072, 1024);
  attn_kernel<<<dim3(1024), 256, 0, stream>>>(qkv, kP, vB, attn);
  gemm_bf16<0, 64, 128><<<512, 256, 0, stream>>>(attn, woT, bo, attnout, nullptr, nullptr, nullptr, 4096, 1024, 1024);
  gemm_bf16<2, 128, 128><<<1024, 256, 0, stream>>>(attnout, w1T, b1, hbuf, nullptr, nullptr, nullptr, 4096, 4096, 1024);
  gemm_bf16<3, 128, 128><<<512, 256, 0, stream>>>(hbuf, w2T, nullptr, nullptr, nullptr, nullptr, ws, 4096, 1024, 4096);
  ln_kernel<<<4096, 256, 0, stream>>>(attnout, P0, P1, b2, gamma, beta, out);
}